// Round 15
// baseline (379.025 us; speedup 1.0000x reference)
//
#include <hip/hip_runtime.h>
#include <stdint.h>

#define NN 50000
#define EE 625000
#define PE (EE + 15*NN + 64)   // padded CSR slots (each node padded to mult of 16)
#define CC 128
#define HH 256
#define LL 4
#define NPAD 50048       // multiple of 64 for k_om tiles
#define NBLK (NPAD/64)   // 782 k_om blocks
#define R2 32            // partial2 rows

typedef __attribute__((ext_vector_type(4))) int   i32x4;
typedef __attribute__((ext_vector_type(2))) short v2s;

// Everything lives on the k/16 grid, k in [-128,127]; rintf == round-half-even
// == jnp.round. All GEMM operands are small ints -> i8 MFMA with i32 accum is
// EXACT (|sum| <= 127*128*256 = 4.2e6), and (float)acc < 2^24 is exact too.
// Edge-feature chain is EXACT INTEGER math: S = dot4(i8,i8)+16kb (<2^17) and
// rq16(t) == clip((t + 7 + ((t>>4)&1)) >> 4) (integer round-half-even).
// Packed i16 message math is exact: |h+e| <= 256, acc <= 127*deg << 32767.
// eqt PAD bytes are -128 so relu(h-128) == 0: pads self-annihilate (guard-free).
__device__ __forceinline__ float qbf(float x){
  return fminf(127.f, fmaxf(-128.f, rintf(x*16.f)));
}
__device__ __forceinline__ float rq16(float t){
  return fminf(127.f, fmaxf(-128.f, rintf(t*0.0625f)));
}
__device__ __forceinline__ int rne16c(int t){   // clip(RNE(t/16), -128, 127)
  int q = (t + 7 + ((t>>4)&1)) >> 4;
  return min(max(q, -128), 127);
}
__device__ __forceinline__ int dot4b(int q, int w, int c){
#if __has_builtin(__builtin_amdgcn_sdot4)
  return __builtin_amdgcn_sdot4(q, w, c, false);
#else
  int s = c;
  #pragma unroll
  for (int i=0;i<4;++i)
    s += ((int)(signed char)((q >> (8*i)) & 0xff)) *
         ((int)(signed char)((w >> (8*i)) & 0xff));
  return s;
#endif
}

// ---------------- param quantization ----------------
__global__ void k_qbig(const float* __restrict__ W1, const float* __restrict__ W2,
                       signed char* __restrict__ w1q8, signed char* __restrict__ w2q8){
  int i = blockIdx.x*256 + threadIdx.x;
  if (i >= LL*CC*HH) return;
  {
    float v = qbf(W1[i]);
    int l = i / (CC*HH); int r = i - l*CC*HH; int c = r / HH; int hh = r - c*HH;
    w1q8[((size_t)l*HH + hh)*CC + c] = (signed char)v;
  }
  {
    float v = qbf(W2[i]);
    int l = i / (HH*CC); int r = i - l*HH*CC; int hh = r / CC; int c = r - hh*CC;
    w2q8[((size_t)l*CC + c)*HH + hh] = (signed char)v;
  }
}

struct QS { const float* s; float* d; int n; float m; };
struct QSArgs { QS q[10]; };

__global__ void k_qsmall(QSArgs a){
  for (int r=0;r<10;++r){
    QS qs = a.q[r];
    for (int i = blockIdx.x*blockDim.x + threadIdx.x; i < qs.n; i += gridDim.x*blockDim.x)
      qs.d[i] = qs.m * qbf(qs.s[i]);
  }
}

// integer per-channel edge-encoder params: {packed 4x i8 weights, 16*kb, kw, 16*kbb}
__global__ void k_epki(const float* __restrict__ eW, const float* __restrict__ eb,
                       const float* __restrict__ bnw, const float* __restrict__ bnb,
                       int4* __restrict__ epk){
  int c = threadIdx.x;
  int w0 = (int)qbf(eW[c])      & 0xff;
  int w1 = (int)qbf(eW[CC+c])   & 0xff;
  int w2 = (int)qbf(eW[2*CC+c]) & 0xff;
  int w3 = (int)qbf(eW[3*CC+c]) & 0xff;
  epk[c] = make_int4(w0 | (w1<<8) | (w2<<16) | (w3<<24),
                     16 * (int)qbf(eb[c]),
                     (int)qbf(bnw[c]),
                     16 * (int)qbf(bnb[c]));
}

// ---------------- node encoder ----------------
__global__ __launch_bounds__(256) void k_node_enc(
    const float* __restrict__ x, const float* __restrict__ nW,
    const float* __restrict__ nb16, const float* __restrict__ bnw,
    const float* __restrict__ bnb16, short* __restrict__ h0,
    short* __restrict__ hq16){
  int idx = blockIdx.x*256 + threadIdx.x;          // grid exact: N*C/256
  int n = idx >> 7, c = idx & 127;
  float x0 = qbf(x[n*3]), x1 = qbf(x[n*3+1]), x2 = qbf(x[n*3+2]);
  float S = x0*nW[c] + x1*nW[CC+c] + x2*nW[2*CC+c];
  float v1 = rq16(S + nb16[c]);
  float v2 = rq16(v1*bnw[c] + bnb16[c]);
  h0[idx] = (short)v2;
  hq16[idx] = (short)v2;   // already in [-128,127] (clamped copy)
}

// ---------------- padded CSR build ----------------
__global__ void k_deg(const int* __restrict__ ei, int* __restrict__ deg){
  int e = blockIdx.x*256 + threadIdx.x;
  if (e < EE) atomicAdd(&deg[ei[EE + e]], 1);
}

// scan of PADDED degrees (deg rounded up to multiple of 16)
__global__ __launch_bounds__(256) void k_scanA(const int* __restrict__ deg,
                                               int* __restrict__ offI,
                                               int* __restrict__ btot){
  __shared__ int sh[256];
  int t = threadIdx.x;
  int base = blockIdx.x*1024 + t*4;
  int v[4]; int s = 0;
  #pragma unroll
  for (int i=0;i<4;++i){
    v[i] = (base+i < NN) ? ((deg[base+i] + 15) & ~15) : 0;
    s += v[i];
  }
  sh[t] = s; __syncthreads();
  for (int off=1; off<256; off<<=1){
    int xv = (t>=off) ? sh[t-off] : 0;
    __syncthreads();
    sh[t] += xv;
    __syncthreads();
  }
  int run = (t>0) ? sh[t-1] : 0;
  #pragma unroll
  for (int i=0;i<4;++i){ run += v[i]; if (base+i < NN) offI[base+i] = run; }
  if (t==255) btot[blockIdx.x] = sh[255];
}

__global__ void k_scanB(const int* __restrict__ btot, int* __restrict__ boff, int nblk){
  if (threadIdx.x==0 && blockIdx.x==0){
    int run = 0;
    for (int b=0;b<nblk;++b){ int v = btot[b]; boff[b] = run; run += v; }
  }
}

__global__ void k_scanC(const int* __restrict__ boff, const int* __restrict__ deg,
                        int* __restrict__ offI, int* __restrict__ cursor){
  int i = blockIdx.x*256 + threadIdx.x;
  if (i < NN){
    int v = offI[i] + boff[i>>10];       // padded inclusive prefix
    offI[i] = v;
    cursor[i] = v - ((deg[i] + 15) & ~15);   // padded segment start (16-aligned)
  }
}

// fill CSR: ONE 8B scatter per edge into padded layout; pads stay zeroed
// (adjq memset to 0: srcoff 0 -> safe dup reads of hq16 row 0)
__global__ void k_fill(const int* __restrict__ ei, const float* __restrict__ ea,
                       int* __restrict__ cursor, int2* __restrict__ adjq){
  int e = blockIdx.x*256 + threadIdx.x;
  if (e < EE){
    int tgt = ei[EE + e];
    int p = atomicAdd(&cursor[tgt], 1);
    float4 v = ((const float4*)ea)[e];
    int b0 = (int)qbf(v.x) & 0xff, b1 = (int)qbf(v.y) & 0xff;
    int b2 = (int)qbf(v.z) & 0xff, b3 = (int)qbf(v.w) & 0xff;
    adjq[p] = make_int2(ei[e] * CC, b0 | (b1<<8) | (b2<<16) | (b3<<24));
  }
}

// ---------------- per-layer message+aggregate (gather CSR, no atomics) ------
// one wave per node, 2 channels per lane; padded 16-edge chunks.
// eq_t layout: [chunk][channel][16 edges] bytes. Pads written as -128.
// MODE 0: recompute edge features (exact int chain) + write eq_t; guard j<rem
// MODE 1: guard-free packed-i16 path: 2 b128 eqt loads, v_perm extract,
//         pk_add/pk_max/pk_min/pk_acc (pads self-annihilate via e=-128)
// MODE 2: recompute-only fallback
template<int MODE>
__global__ __launch_bounds__(256) void k_msg(
    const int* __restrict__ offI, const int* __restrict__ deg_,
    const int2* __restrict__ adjq, const int4* __restrict__ epk,
    signed char* __restrict__ eqt,
    const short* __restrict__ hq16, signed char* __restrict__ uq){
  int n = blockIdx.x*4 + (threadIdx.x >> 6);
  int lane = threadIdx.x & 63;
  int c0 = lane*2;
  int4 P0, P1;
  if (MODE != 1){ P0 = epk[c0]; P1 = epk[c0+1]; }
  int d = deg_[n];
  int degP = (d + 15) & ~15;
  int startP = offI[n] - degP;
  int acc0 = 0, acc1 = 0;
  v2s accp = v2s{0, 0};
  for (int k = 0; k < degP; k += 16){
    int base = startP + k;
    int2 a = adjq[base + (lane & 15)];   // 16 slots, all initialized (pads=0)
    v2s hvv[16];
    #pragma unroll
    for (int j=0;j<16;++j){
      int soj = __builtin_amdgcn_readlane(a.x, j);
      hvv[j] = *(const v2s*)(hq16 + soj + c0);   // clamped pair, 4B
    }
    if (MODE == 1){
      const i32x4* ep = (const i32x4*)(eqt + ((size_t)(base >> 4) << 11));
      i32x4 ev0 = ep[c0];
      i32x4 ev1 = ep[c0 + 1];
      #pragma unroll
      for (int j=0;j<16;++j){
        uint sel = 0x0Cu | ((uint)(4+(j&3))<<8) | (0x0Cu<<16) | ((uint)(j&3)<<24);
        uint pr = __builtin_amdgcn_perm((uint)ev0[j>>2], (uint)ev1[j>>2], sel);
        v2s ev = *(v2s*)&pr;
        ev = ev >> 8;                      // pk_ashrrev_i16: sign-extended {e0,e1}
        v2s s = hvv[j] + ev;               // pk_add_i16
        s = __builtin_elementwise_max(s, v2s{0, 0});
        s = __builtin_elementwise_min(s, v2s{127, 127});
        accp += s;                         // pads: e=-128 -> s=0, no guard needed
      }
    } else {
      int rem = min(d - k, 16);            // wave-uniform
      int qk[16];
      #pragma unroll
      for (int j=0;j<16;++j) qk[j] = __builtin_amdgcn_readlane(a.y, j);
      uint pk0[4] = {0x80808080u,0x80808080u,0x80808080u,0x80808080u};
      uint pk1[4] = {0x80808080u,0x80808080u,0x80808080u,0x80808080u};
      #pragma unroll
      for (int j=0;j<16;++j){
        if (j < rem){                    // wave-uniform branch
          int h0 = hvv[j].x;
          int h1 = hvv[j].y;
          int q = qk[j];
          int v10 = rne16c(dot4b(q, P0.x, P0.y));
          int v11 = rne16c(dot4b(q, P1.x, P1.y));
          int e0 = rne16c(v10*P0.z + P0.w);
          int e1 = rne16c(v11*P1.z + P1.w);
          if (MODE == 0){
            uint sh = 8*(j&3), msk = 0xffu << sh;
            pk0[j>>2] = (pk0[j>>2] & ~msk) | (((uint)(e0 & 0xff)) << sh);
            pk1[j>>2] = (pk1[j>>2] & ~msk) | (((uint)(e1 & 0xff)) << sh);
          }
          acc0 += min(max(h0 + e0, 0), 127);
          acc1 += min(max(h1 + e1, 0), 127);
        }
      }
      if (MODE == 0){
        i32x4* ep = (i32x4*)(eqt + ((size_t)(base >> 4) << 11));
        i32x4 w0 = { (int)pk0[0], (int)pk0[1], (int)pk0[2], (int)pk0[3] };
        i32x4 w1 = { (int)pk1[0], (int)pk1[1], (int)pk1[2], (int)pk1[3] };
        ep[c0]     = w0;
        ep[c0 + 1] = w1;
      }
    }
  }
  if (MODE == 1){ acc0 = accp.x; acc1 = accp.y; }
  int ua = min(acc0, 127), ub = min(acc1, 127);
  *(ushort*)(uq + (size_t)n*CC + c0) = (ushort)((ua & 0xff) | ((ub & 0xff) << 8));
}

// ---------------- fused ObjectModel via i8 MFMA (exact) ----------------
// 64-node tile, 4 waves. B-fragments (weights) preloaded into registers;
// K-loops are LDS-read + MFMA only. i32 accum, float requant epilogue.
__global__ __launch_bounds__(256, 3) void k_om(
    int l, const signed char* __restrict__ uq,
    const signed char* __restrict__ w1q8, const float* __restrict__ b1q16,
    const float* __restrict__ bnwf, const float* __restrict__ bnb16,
    const signed char* __restrict__ w2q8, const float* __restrict__ b2q16,
    const short* __restrict__ h_in, short* __restrict__ h_out,
    short* __restrict__ hq16, int* __restrict__ partial){
  __shared__ signed char uL[64][144];   // 9.2KB, pitch 16-aligned
  __shared__ signed char zL[64][272];   // 17.4KB
  int t = threadIdx.x;
  int nb = blockIdx.x * 64;
  {  // stage u tile (64x128 i8): 32B per thread
    const i32x4* src = (const i32x4*)(uq + (size_t)nb*CC + t*32);
    int flat = t*32; int r = flat >> 7, c = flat & 127;
    *(i32x4*)&uL[r][c]      = src[0];
    *(i32x4*)&uL[r][c + 16] = src[1];
  }
  int lane = t & 63, wv = t >> 6;
  int lr = lane & 15, lk = lane >> 4;
  // preload W1 B-frags: wave wv covers hcols wv*64 + ci*16 + lr; K=128 in 2 steps
  const signed char* W1p = w1q8 + (size_t)l*HH*CC;
  i32x4 w1f[2][4];
  #pragma unroll
  for (int ks=0; ks<2; ++ks)
    #pragma unroll
    for (int ci=0; ci<4; ++ci)
      w1f[ks][ci] = *(const i32x4*)(W1p + (size_t)(wv*64 + ci*16 + lr)*CC + ks*64 + lk*16);
  __syncthreads();

  // ---- GEMM1: z1[64 x 256] = u[64 x 128] @ W1 (i8, exact) ----
  i32x4 acc[4][4];
  #pragma unroll
  for (int mi=0;mi<4;++mi)
    #pragma unroll
    for (int ci=0;ci<4;++ci) acc[mi][ci] = (i32x4){0,0,0,0};
  #pragma unroll
  for (int ks=0; ks<2; ++ks){
    i32x4 av[4];
    #pragma unroll
    for (int mi=0;mi<4;++mi) av[mi] = *(const i32x4*)&uL[mi*16+lr][ks*64 + lk*16];
    #pragma unroll
    for (int mi=0;mi<4;++mi)
      #pragma unroll
      for (int ci=0;ci<4;++ci)
        acc[mi][ci] = __builtin_amdgcn_mfma_i32_16x16x64_i8(av[mi], w1f[ks][ci], acc[mi][ci], 0,0,0);
  }
  // epilogue1: requant + BN + ReLU -> zL (i8)
  #pragma unroll
  for (int ci=0;ci<4;++ci){
    int hcol = wv*64 + ci*16 + lr;
    float b1 = b1q16[l*HH + hcol];
    float bw = bnwf[l*HH + hcol];
    float bb = bnb16[l*HH + hcol];
    #pragma unroll
    for (int mi=0;mi<4;++mi){
      #pragma unroll
      for (int r=0;r<4;++r){
        float v1 = rq16((float)acc[mi][ci][r] + b1);
        float v2 = fmaxf(rq16(v1*bw + bb), 0.f);
        zL[mi*16 + lk*4 + r][hcol] = (signed char)v2;
      }
    }
  }
  // preload W2 B-frags (after acc freed): wave covers ccols wv*32 + ci*16 + lr; K=256
  const signed char* W2p = w2q8 + (size_t)l*CC*HH;
  i32x4 w2f[4][2];
  #pragma unroll
  for (int ks=0; ks<4; ++ks)
    #pragma unroll
    for (int ci=0; ci<2; ++ci)
      w2f[ks][ci] = *(const i32x4*)(W2p + (size_t)(wv*32 + ci*16 + lr)*HH + ks*64 + lk*16);
  __syncthreads();

  // ---- GEMM2: z2[64 x 128] = z1[64 x 256] @ W2 (i8, exact) ----
  i32x4 a2[4][2];
  #pragma unroll
  for (int mi=0;mi<4;++mi){ a2[mi][0] = (i32x4){0,0,0,0}; a2[mi][1] = (i32x4){0,0,0,0}; }
  #pragma unroll
  for (int ks=0; ks<4; ++ks){
    i32x4 av[4];
    #pragma unroll
    for (int mi=0;mi<4;++mi) av[mi] = *(const i32x4*)&zL[mi*16+lr][ks*64 + lk*16];
    #pragma unroll
    for (int mi=0;mi<4;++mi)
      #pragma unroll
      for (int ci=0;ci<2;++ci)
        a2[mi][ci] = __builtin_amdgcn_mfma_i32_16x16x64_i8(av[mi], w2f[ks][ci], a2[mi][ci], 0,0,0);
  }
  // epilogue2: requant + residual; write h16 + clamped i16 copy (+ pool partials)
  int psum[2] = {0, 0};
  #pragma unroll
  for (int ci=0;ci<2;++ci){
    int ccol = wv*32 + ci*16 + lr;
    float b2 = b2q16[l*CC + ccol];
    #pragma unroll
    for (int mi=0;mi<4;++mi){
      #pragma unroll
      for (int r=0;r<4;++r){
        int node = nb + mi*16 + lk*4 + r;
        float v = rq16((float)a2[mi][ci][r] + b2);
        int hn = (int)h_in[(size_t)node*CC + ccol] + (int)v;
        if (node < NN){
          h_out[(size_t)node*CC + ccol] = (short)hn;
          hq16[(size_t)node*CC + ccol] = (short)min(max(hn, -128), 127);
          psum[ci] += hn;
        }
      }
    }
  }
  if (partial){
    #pragma unroll
    for (int ci=0;ci<2;++ci){
      int s = psum[ci];
      s += __shfl_xor(s, 16);   // combine lk pairs (exact int adds)
      s += __shfl_xor(s, 32);
      if (lk == 0)
        partial[blockIdx.x*CC + wv*32 + ci*16 + lr] = s;
    }
  }
}

// ---------------- pool reduction stage 1: 782 rows -> 32 rows ----------------
__global__ __launch_bounds__(256) void k_red(
    const int* __restrict__ partial, int* __restrict__ partial2){
  int t = threadIdx.x;
  int c = t & 127;
  int sub = blockIdx.x*2 + (t >> 7);   // 32 sub-chunks
  int s = 0;
  for (int b = sub; b < NBLK; b += R2) s += partial[b*CC + c];
  partial2[sub*CC + c] = s;
}

// ---------------- head: reduce partials + fc + sigmoid ----------------
__global__ __launch_bounds__(256) void k_final(
    const int* __restrict__ partial2, const float* __restrict__ fcwf,
    const float* __restrict__ fcb16, float* __restrict__ out){
  __shared__ int ired[128];
  __shared__ float red[128];
  int t = threadIdx.x;            // 256 threads
  int c = t & 127, half = t >> 7;
  int s = 0;
  #pragma unroll
  for (int b = half; b < R2; b += 2) s += partial2[b*CC + c];
  if (half) ired[c] = s;
  __syncthreads();
  if (!half){
    int sc = s + ired[c];
    double m = (double)sc / (double)NN;
    float pq = fminf(127.f, fmaxf(-128.f, (float)rint(m)));
    red[c] = pq * fcwf[c];
  }
  __syncthreads();
  for (int o=64;o>0;o>>=1){ if (t<o) red[t] += red[t+o]; __syncthreads(); }
  if (t==0){
    float v = rq16(red[0] + fcb16[0]);
    float o1 = v * 0.0625f;
    float sg = 1.f/(1.f + expf(-o1));
    float oq = fminf(127.f, fmaxf(-128.f, rintf(sg*16.f)));
    out[0] = oq * 0.0625f;
  }
}

extern "C" void kernel_launch(void* const* d_in, const int* in_sizes, int n_in,
                              void* d_out, int out_size, void* d_ws, size_t ws_size,
                              hipStream_t stream){
  (void)in_sizes; (void)n_in; (void)out_size;
  const float* x   = (const float*)d_in[0];
  const float* ea  = (const float*)d_in[1];
  const int*   ei  = (const int*)d_in[2];
  const float* W1  = (const float*)d_in[11];
  const float* W2  = (const float*)d_in[15];

  char* w = (char*)d_ws;
  auto alloc = [&](size_t bytes)->char*{
    char* p = w; w += (bytes + 255) & ~(size_t)255; return p;
  };
  short* h0        = (short*)alloc((size_t)NPAD*CC*2);
  short* h1        = (short*)alloc((size_t)NPAD*CC*2);
  short* hq16      = (short*)alloc((size_t)NPAD*CC*2);
  signed char* uq  = (signed char*)alloc((size_t)NPAD*CC);
  int2* adjq       = (int2*)alloc((size_t)PE*8);
  int* deg         = (int*)alloc(NN*4);
  int* offI        = (int*)alloc(NN*4);
  int* cursor      = (int*)alloc(NN*4);
  int* btot        = (int*)alloc(64*4);
  int* boff        = (int*)alloc(64*4);
  int* partial     = (int*)alloc((size_t)NBLK*CC*4);
  int* partial2    = (int*)alloc((size_t)R2*CC*4);
  signed char* w1q8= (signed char*)alloc((size_t)LL*CC*HH);
  signed char* w2q8= (signed char*)alloc((size_t)LL*CC*HH);
  float* nodeWf    = (float*)alloc(3*CC*4);
  float* nb16f     = (float*)alloc(CC*4);
  float* nbnwf     = (float*)alloc(CC*4);
  float* nbnb16f   = (float*)alloc(CC*4);
  float* b1q16f    = (float*)alloc(LL*HH*4);
  float* bnwf      = (float*)alloc(LL*HH*4);
  float* bnb16f    = (float*)alloc(LL*HH*4);
  float* b2q16f    = (float*)alloc(LL*CC*4);
  float* fcwf      = (float*)alloc(CC*4);
  float* fcb16f    = (float*)alloc(256);
  int4* epk        = (int4*)alloc(CC*16);
  size_t base_used = (size_t)(w - (char*)d_ws);
  // chunk-transposed edge features: 128B per padded slot (worst case ~176MB)
  bool TEQ = (ws_size >= base_used + (size_t)PE*CC + (16u<<20));
  signed char* eqt = TEQ ? (signed char*)alloc((size_t)PE*CC) : nullptr;

  hipMemsetAsync(deg, 0, NN*4, stream);
  hipMemsetAsync(adjq, 0, (size_t)PE*8, stream);   // zero pads (safe dup reads)

  k_qbig<<<(LL*CC*HH + 255)/256, 256, 0, stream>>>(W1, W2, w1q8, w2q8);

  QSArgs qa;
  auto setq = [&](int r, int idx, float* d, int n, float m){
    qa.q[r].s = (const float*)d_in[idx]; qa.q[r].d = d; qa.q[r].n = n; qa.q[r].m = m;
  };
  setq(0, 3,  nodeWf,  3*CC, 1.f);
  setq(1, 4,  nb16f,   CC,   16.f);
  setq(2, 7,  nbnwf,   CC,   1.f);
  setq(3, 8,  nbnb16f, CC,   16.f);
  setq(4, 12, b1q16f,  LL*HH, 16.f);
  setq(5, 13, bnwf,    LL*HH, 1.f);
  setq(6, 14, bnb16f,  LL*HH, 16.f);
  setq(7, 16, b2q16f,  LL*CC, 16.f);
  setq(8, 17, fcwf,    CC,   1.f);
  setq(9, 18, fcb16f,  1,    16.f);
  k_qsmall<<<4, 256, 0, stream>>>(qa);
  k_epki<<<1, 128, 0, stream>>>((const float*)d_in[5], (const float*)d_in[6],
                                (const float*)d_in[9], (const float*)d_in[10], epk);

  k_node_enc<<<(NN*CC)/256, 256, 0, stream>>>(x, nodeWf, nb16f, nbnwf, nbnb16f, h0, hq16);
  k_deg<<<(EE+255)/256, 256, 0, stream>>>(ei, deg);
  int nblk = (NN + 1023)/1024;
  k_scanA<<<nblk, 256, 0, stream>>>(deg, offI, btot);
  k_scanB<<<1, 64, 0, stream>>>(btot, boff, nblk);
  k_scanC<<<(NN+255)/256, 256, 0, stream>>>(boff, deg, offI, cursor);
  k_fill<<<(EE+255)/256, 256, 0, stream>>>(ei, ea, cursor, adjq);

  for (int l=0;l<LL;++l){
    const short* hi = (l & 1) ? h1 : h0;
    short* ho       = (l & 1) ? h0 : h1;
    if (!TEQ)
      k_msg<2><<<NN/4, 256, 0, stream>>>(offI, deg, adjq, epk, eqt, hq16, uq);
    else if (l == 0)
      k_msg<0><<<NN/4, 256, 0, stream>>>(offI, deg, adjq, epk, eqt, hq16, uq);
    else
      k_msg<1><<<NN/4, 256, 0, stream>>>(offI, deg, adjq, epk, eqt, hq16, uq);
    k_om<<<NBLK, 256, 0, stream>>>(l, uq, w1q8, b1q16f, bnwf, bnb16f,
                                   w2q8, b2q16f, hi, ho, hq16,
                                   (l == LL-1) ? partial : nullptr);
  }
  k_red<<<R2/2, 256, 0, stream>>>(partial, partial2);
  k_final<<<1, 256, 0, stream>>>(partial2, fcwf, fcb16f, (float*)d_out);
}

// Round 16
// 348.870 us; speedup vs baseline: 1.0864x; 1.0864x over previous
//
#include <hip/hip_runtime.h>
#include <stdint.h>

#define NN 50000
#define EE 625000
#define PE (EE + 15*NN + 64)   // padded CSR slots (each node padded to mult of 16)
#define CC 128
#define HH 256
#define LL 4
#define NPAD 50048       // multiple of 64 for k_om tiles
#define NBLK (NPAD/64)   // 782 k_om blocks
#define R2 32            // partial2 rows

typedef __attribute__((ext_vector_type(4))) int   i32x4;
typedef __attribute__((ext_vector_type(2))) short v2s;

// Everything lives on the k/16 grid, k in [-128,127]; rintf == round-half-even
// == jnp.round. All GEMM operands are small ints -> i8 MFMA with i32 accum is
// EXACT (|sum| <= 127*128*256 = 4.2e6), and (float)acc < 2^24 is exact too.
// Edge-feature chain is EXACT INTEGER math: S = dot4(i8,i8)+16kb (<2^17) and
// rq16(t) == clip((t + 7 + ((t>>4)&1)) >> 4) (integer round-half-even).
// Packed i16 message math exact: |h+e| <= 255, acc <= 127*deg << 32767
// (deg ~ Poisson(12.5); i16 safe for deg <= 258).
// eqt PAD bytes are -128 so relu(h-128)==0: pads self-annihilate (guard-free).
__device__ __forceinline__ float qbf(float x){
  return fminf(127.f, fmaxf(-128.f, rintf(x*16.f)));
}
__device__ __forceinline__ float rq16(float t){
  return fminf(127.f, fmaxf(-128.f, rintf(t*0.0625f)));
}
__device__ __forceinline__ int rne16c(int t){   // clip(RNE(t/16), -128, 127)
  int q = (t + 7 + ((t>>4)&1)) >> 4;
  return min(max(q, -128), 127);
}
__device__ __forceinline__ int dot4b(int q, int w, int c){
#if __has_builtin(__builtin_amdgcn_sdot4)
  return __builtin_amdgcn_sdot4(q, w, c, false);
#else
  int s = c;
  #pragma unroll
  for (int i=0;i<4;++i)
    s += ((int)(signed char)((q >> (8*i)) & 0xff)) *
         ((int)(signed char)((w >> (8*i)) & 0xff));
  return s;
#endif
}

// ---------------- param quantization ----------------
__global__ void k_qbig(const float* __restrict__ W1, const float* __restrict__ W2,
                       signed char* __restrict__ w1q8, signed char* __restrict__ w2q8){
  int i = blockIdx.x*256 + threadIdx.x;
  if (i >= LL*CC*HH) return;
  {
    float v = qbf(W1[i]);
    int l = i / (CC*HH); int r = i - l*CC*HH; int c = r / HH; int hh = r - c*HH;
    w1q8[((size_t)l*HH + hh)*CC + c] = (signed char)v;
  }
  {
    float v = qbf(W2[i]);
    int l = i / (HH*CC); int r = i - l*HH*CC; int hh = r / CC; int c = r - hh*CC;
    w2q8[((size_t)l*CC + c)*HH + hh] = (signed char)v;
  }
}

struct QS { const float* s; float* d; int n; float m; };
struct QSArgs { QS q[10]; };

__global__ void k_qsmall(QSArgs a){
  for (int r=0;r<10;++r){
    QS qs = a.q[r];
    for (int i = blockIdx.x*blockDim.x + threadIdx.x; i < qs.n; i += gridDim.x*blockDim.x)
      qs.d[i] = qs.m * qbf(qs.s[i]);
  }
}

// integer per-channel edge-encoder params: {packed 4x i8 weights, 16*kb, kw, 16*kbb}
__global__ void k_epki(const float* __restrict__ eW, const float* __restrict__ eb,
                       const float* __restrict__ bnw, const float* __restrict__ bnb,
                       int4* __restrict__ epk){
  int c = threadIdx.x;
  int w0 = (int)qbf(eW[c])      & 0xff;
  int w1 = (int)qbf(eW[CC+c])   & 0xff;
  int w2 = (int)qbf(eW[2*CC+c]) & 0xff;
  int w3 = (int)qbf(eW[3*CC+c]) & 0xff;
  epk[c] = make_int4(w0 | (w1<<8) | (w2<<16) | (w3<<24),
                     16 * (int)qbf(eb[c]),
                     (int)qbf(bnw[c]),
                     16 * (int)qbf(bnb[c]));
}

// ---------------- node encoder ----------------
__global__ __launch_bounds__(256) void k_node_enc(
    const float* __restrict__ x, const float* __restrict__ nW,
    const float* __restrict__ nb16, const float* __restrict__ bnw,
    const float* __restrict__ bnb16, short* __restrict__ h0,
    signed char* __restrict__ hq8){
  int idx = blockIdx.x*256 + threadIdx.x;          // grid exact: N*C/256
  int n = idx >> 7, c = idx & 127;
  float x0 = qbf(x[n*3]), x1 = qbf(x[n*3+1]), x2 = qbf(x[n*3+2]);
  float S = x0*nW[c] + x1*nW[CC+c] + x2*nW[2*CC+c];
  float v1 = rq16(S + nb16[c]);
  float v2 = rq16(v1*bnw[c] + bnb16[c]);
  h0[idx] = (short)v2;
  hq8[idx] = (signed char)v2;   // already in [-128,127]
}

// ---------------- padded CSR build ----------------
__global__ void k_deg(const int* __restrict__ ei, int* __restrict__ deg){
  int e = blockIdx.x*256 + threadIdx.x;
  if (e < EE) atomicAdd(&deg[ei[EE + e]], 1);
}

// scan of PADDED degrees (deg rounded up to multiple of 16)
__global__ __launch_bounds__(256) void k_scanA(const int* __restrict__ deg,
                                               int* __restrict__ offI,
                                               int* __restrict__ btot){
  __shared__ int sh[256];
  int t = threadIdx.x;
  int base = blockIdx.x*1024 + t*4;
  int v[4]; int s = 0;
  #pragma unroll
  for (int i=0;i<4;++i){
    v[i] = (base+i < NN) ? ((deg[base+i] + 15) & ~15) : 0;
    s += v[i];
  }
  sh[t] = s; __syncthreads();
  for (int off=1; off<256; off<<=1){
    int xv = (t>=off) ? sh[t-off] : 0;
    __syncthreads();
    sh[t] += xv;
    __syncthreads();
  }
  int run = (t>0) ? sh[t-1] : 0;
  #pragma unroll
  for (int i=0;i<4;++i){ run += v[i]; if (base+i < NN) offI[base+i] = run; }
  if (t==255) btot[blockIdx.x] = sh[255];
}

__global__ void k_scanB(const int* __restrict__ btot, int* __restrict__ boff, int nblk){
  if (threadIdx.x==0 && blockIdx.x==0){
    int run = 0;
    for (int b=0;b<nblk;++b){ int v = btot[b]; boff[b] = run; run += v; }
  }
}

__global__ void k_scanC(const int* __restrict__ boff, const int* __restrict__ deg,
                        int* __restrict__ offI, int* __restrict__ cursor){
  int i = blockIdx.x*256 + threadIdx.x;
  if (i < NN){
    int v = offI[i] + boff[i>>10];       // padded inclusive prefix
    offI[i] = v;
    cursor[i] = v - ((deg[i] + 15) & ~15);   // padded segment start (16-aligned)
  }
}

// fill CSR: ONE 8B scatter per edge into padded layout; pads stay zeroed
// (adjq memset to 0: srcoff 0 -> safe dup reads of hq8 row 0)
__global__ void k_fill(const int* __restrict__ ei, const float* __restrict__ ea,
                       int* __restrict__ cursor, int2* __restrict__ adjq){
  int e = blockIdx.x*256 + threadIdx.x;
  if (e < EE){
    int tgt = ei[EE + e];
    int p = atomicAdd(&cursor[tgt], 1);
    float4 v = ((const float4*)ea)[e];
    int b0 = (int)qbf(v.x) & 0xff, b1 = (int)qbf(v.y) & 0xff;
    int b2 = (int)qbf(v.z) & 0xff, b3 = (int)qbf(v.w) & 0xff;
    adjq[p] = make_int2(ei[e] * CC, b0 | (b1<<8) | (b2<<16) | (b3<<24));
  }
}

// ---------------- per-layer message+aggregate (gather CSR, no atomics) ------
// one wave per node, 2 channels per lane; padded 16-edge chunks.
// eq_t layout: [chunk][channel][16 edges] bytes. PAD bytes = -128.
// MODE 0: recompute edge features (exact int chain) + write eq_t; guard j<rem
// MODE 1: guard-free packed-i16: 2B hq8 gathers + 2 b128 eqt loads, v_perm
//         unpack, pk math (pads self-annihilate via e=-128)
// MODE 2: recompute-only fallback
template<int MODE>
__global__ __launch_bounds__(256) void k_msg(
    const int* __restrict__ offI, const int* __restrict__ deg_,
    const int2* __restrict__ adjq, const int4* __restrict__ epk,
    signed char* __restrict__ eqt,
    const signed char* __restrict__ hq8, signed char* __restrict__ uq){
  int n = blockIdx.x*4 + (threadIdx.x >> 6);
  int lane = threadIdx.x & 63;
  int c0 = lane*2;
  int4 P0, P1;
  if (MODE != 1){ P0 = epk[c0]; P1 = epk[c0+1]; }
  int d = deg_[n];
  int degP = (d + 15) & ~15;
  int startP = offI[n] - degP;
  int acc0 = 0, acc1 = 0;
  v2s accp = v2s{0, 0};
  for (int k = 0; k < degP; k += 16){
    int base = startP + k;
    int2 a = adjq[base + (lane & 15)];   // 16 slots, all initialized (pads=0)
    uint hp[16];
    #pragma unroll
    for (int j=0;j<16;++j){
      int soj = __builtin_amdgcn_readlane(a.x, j);
      hp[j] = *(const ushort*)(hq8 + soj + c0);   // 2B: byte pair {h0,h1}
    }
    if (MODE == 1){
      const i32x4* ep = (const i32x4*)(eqt + ((size_t)(base >> 4) << 11));
      i32x4 ev0 = ep[c0];
      i32x4 ev1 = ep[c0 + 1];
      #pragma unroll
      for (int j=0;j<16;++j){
        // h: {?,h0,?,h1} bytes then >>8 sign-extends to {h0,h1} i16
        uint hx = __builtin_amdgcn_perm(hp[j], hp[j], 0x010C000Cu);
        v2s hv = *(v2s*)&hx; hv = hv >> 8;
        uint sel = 0x0Cu | ((uint)(4+(j&3))<<8) | (0x0Cu<<16) | ((uint)(j&3)<<24);
        uint pr = __builtin_amdgcn_perm((uint)ev0[j>>2], (uint)ev1[j>>2], sel);
        v2s ev = *(v2s*)&pr; ev = ev >> 8;       // {e0,e1} i16
        v2s s = hv + ev;                          // pk_add_i16
        s = __builtin_elementwise_max(s, v2s{0, 0});
        s = __builtin_elementwise_min(s, v2s{127, 127});
        accp += s;                  // pads: e=-128 -> s=0, guard-free
      }
    } else {
      int rem = min(d - k, 16);            // wave-uniform
      int qk[16];
      #pragma unroll
      for (int j=0;j<16;++j) qk[j] = __builtin_amdgcn_readlane(a.y, j);
      uint pk0[4] = {0x80808080u,0x80808080u,0x80808080u,0x80808080u};
      uint pk1[4] = {0x80808080u,0x80808080u,0x80808080u,0x80808080u};
      #pragma unroll
      for (int j=0;j<16;++j){
        if (j < rem){                    // wave-uniform branch
          int h0 = (int)(signed char)(hp[j] & 0xff);
          int h1 = (int)(signed char)(hp[j] >> 8);
          int q = qk[j];
          int v10 = rne16c(dot4b(q, P0.x, P0.y));
          int v11 = rne16c(dot4b(q, P1.x, P1.y));
          int e0 = rne16c(v10*P0.z + P0.w);
          int e1 = rne16c(v11*P1.z + P1.w);
          if (MODE == 0){
            uint sh = 8*(j&3), msk = 0xffu << sh;
            pk0[j>>2] = (pk0[j>>2] & ~msk) | (((uint)(e0 & 0xff)) << sh);
            pk1[j>>2] = (pk1[j>>2] & ~msk) | (((uint)(e1 & 0xff)) << sh);
          }
          acc0 += min(max(h0 + e0, 0), 127);
          acc1 += min(max(h1 + e1, 0), 127);
        }
      }
      if (MODE == 0){
        i32x4* ep = (i32x4*)(eqt + ((size_t)(base >> 4) << 11));
        i32x4 w0 = { (int)pk0[0], (int)pk0[1], (int)pk0[2], (int)pk0[3] };
        i32x4 w1 = { (int)pk1[0], (int)pk1[1], (int)pk1[2], (int)pk1[3] };
        ep[c0]     = w0;
        ep[c0 + 1] = w1;
      }
    }
  }
  if (MODE == 1){ acc0 = accp.x; acc1 = accp.y; }
  int ua = min(acc0, 127), ub = min(acc1, 127);
  *(ushort*)(uq + (size_t)n*CC + c0) = (ushort)((ua & 0xff) | ((ub & 0xff) << 8));
}

// ---------------- fused ObjectModel via i8 MFMA (exact) ----------------
// 64-node tile, 4 waves. B-fragments (weights) preloaded into registers;
// K-loops are LDS-read + MFMA only. i32 accum, float requant epilogue.
__global__ __launch_bounds__(256, 3) void k_om(
    int l, const signed char* __restrict__ uq,
    const signed char* __restrict__ w1q8, const float* __restrict__ b1q16,
    const float* __restrict__ bnwf, const float* __restrict__ bnb16,
    const signed char* __restrict__ w2q8, const float* __restrict__ b2q16,
    const short* __restrict__ h_in, short* __restrict__ h_out,
    signed char* __restrict__ hq8, int* __restrict__ partial){
  __shared__ signed char uL[64][144];   // 9.2KB, pitch 16-aligned
  __shared__ signed char zL[64][272];   // 17.4KB
  int t = threadIdx.x;
  int nb = blockIdx.x * 64;
  {  // stage u tile (64x128 i8): 32B per thread
    const i32x4* src = (const i32x4*)(uq + (size_t)nb*CC + t*32);
    int flat = t*32; int r = flat >> 7, c = flat & 127;
    *(i32x4*)&uL[r][c]      = src[0];
    *(i32x4*)&uL[r][c + 16] = src[1];
  }
  int lane = t & 63, wv = t >> 6;
  int lr = lane & 15, lk = lane >> 4;
  // preload W1 B-frags: wave wv covers hcols wv*64 + ci*16 + lr; K=128 in 2 steps
  const signed char* W1p = w1q8 + (size_t)l*HH*CC;
  i32x4 w1f[2][4];
  #pragma unroll
  for (int ks=0; ks<2; ++ks)
    #pragma unroll
    for (int ci=0; ci<4; ++ci)
      w1f[ks][ci] = *(const i32x4*)(W1p + (size_t)(wv*64 + ci*16 + lr)*CC + ks*64 + lk*16);
  __syncthreads();

  // ---- GEMM1: z1[64 x 256] = u[64 x 128] @ W1 (i8, exact) ----
  i32x4 acc[4][4];
  #pragma unroll
  for (int mi=0;mi<4;++mi)
    #pragma unroll
    for (int ci=0;ci<4;++ci) acc[mi][ci] = (i32x4){0,0,0,0};
  #pragma unroll
  for (int ks=0; ks<2; ++ks){
    i32x4 av[4];
    #pragma unroll
    for (int mi=0;mi<4;++mi) av[mi] = *(const i32x4*)&uL[mi*16+lr][ks*64 + lk*16];
    #pragma unroll
    for (int mi=0;mi<4;++mi)
      #pragma unroll
      for (int ci=0;ci<4;++ci)
        acc[mi][ci] = __builtin_amdgcn_mfma_i32_16x16x64_i8(av[mi], w1f[ks][ci], acc[mi][ci], 0,0,0);
  }
  // epilogue1: requant + BN + ReLU -> zL (i8)
  #pragma unroll
  for (int ci=0;ci<4;++ci){
    int hcol = wv*64 + ci*16 + lr;
    float b1 = b1q16[l*HH + hcol];
    float bw = bnwf[l*HH + hcol];
    float bb = bnb16[l*HH + hcol];
    #pragma unroll
    for (int mi=0;mi<4;++mi){
      #pragma unroll
      for (int r=0;r<4;++r){
        float v1 = rq16((float)acc[mi][ci][r] + b1);
        float v2 = fmaxf(rq16(v1*bw + bb), 0.f);
        zL[mi*16 + lk*4 + r][hcol] = (signed char)v2;
      }
    }
  }
  // preload W2 B-frags (after acc freed): wave covers ccols wv*32 + ci*16 + lr; K=256
  const signed char* W2p = w2q8 + (size_t)l*CC*HH;
  i32x4 w2f[4][2];
  #pragma unroll
  for (int ks=0; ks<4; ++ks)
    #pragma unroll
    for (int ci=0; ci<2; ++ci)
      w2f[ks][ci] = *(const i32x4*)(W2p + (size_t)(wv*32 + ci*16 + lr)*HH + ks*64 + lk*16);
  __syncthreads();

  // ---- GEMM2: z2[64 x 128] = z1[64 x 256] @ W2 (i8, exact) ----
  i32x4 a2[4][2];
  #pragma unroll
  for (int mi=0;mi<4;++mi){ a2[mi][0] = (i32x4){0,0,0,0}; a2[mi][1] = (i32x4){0,0,0,0}; }
  #pragma unroll
  for (int ks=0; ks<4; ++ks){
    i32x4 av[4];
    #pragma unroll
    for (int mi=0;mi<4;++mi) av[mi] = *(const i32x4*)&zL[mi*16+lr][ks*64 + lk*16];
    #pragma unroll
    for (int mi=0;mi<4;++mi)
      #pragma unroll
      for (int ci=0;ci<2;++ci)
        a2[mi][ci] = __builtin_amdgcn_mfma_i32_16x16x64_i8(av[mi], w2f[ks][ci], a2[mi][ci], 0,0,0);
  }
  // epilogue2: requant + residual; write h16 + clamped int8 (+ pool partials)
  int psum[2] = {0, 0};
  #pragma unroll
  for (int ci=0;ci<2;++ci){
    int ccol = wv*32 + ci*16 + lr;
    float b2 = b2q16[l*CC + ccol];
    #pragma unroll
    for (int mi=0;mi<4;++mi){
      #pragma unroll
      for (int r=0;r<4;++r){
        int node = nb + mi*16 + lk*4 + r;
        float v = rq16((float)a2[mi][ci][r] + b2);
        int hn = (int)h_in[(size_t)node*CC + ccol] + (int)v;
        if (node < NN){
          h_out[(size_t)node*CC + ccol] = (short)hn;
          hq8[(size_t)node*CC + ccol] = (signed char)min(max(hn, -128), 127);
          psum[ci] += hn;
        }
      }
    }
  }
  if (partial){
    #pragma unroll
    for (int ci=0;ci<2;++ci){
      int s = psum[ci];
      s += __shfl_xor(s, 16);   // combine lk pairs (exact int adds)
      s += __shfl_xor(s, 32);
      if (lk == 0)
        partial[blockIdx.x*CC + wv*32 + ci*16 + lr] = s;
    }
  }
}

// ---------------- pool reduction stage 1: 782 rows -> 32 rows ----------------
__global__ __launch_bounds__(256) void k_red(
    const int* __restrict__ partial, int* __restrict__ partial2){
  int t = threadIdx.x;
  int c = t & 127;
  int sub = blockIdx.x*2 + (t >> 7);   // 32 sub-chunks
  int s = 0;
  for (int b = sub; b < NBLK; b += R2) s += partial[b*CC + c];
  partial2[sub*CC + c] = s;
}

// ---------------- head: reduce partials + fc + sigmoid ----------------
__global__ __launch_bounds__(256) void k_final(
    const int* __restrict__ partial2, const float* __restrict__ fcwf,
    const float* __restrict__ fcb16, float* __restrict__ out){
  __shared__ int ired[128];
  __shared__ float red[128];
  int t = threadIdx.x;            // 256 threads
  int c = t & 127, half = t >> 7;
  int s = 0;
  #pragma unroll
  for (int b = half; b < R2; b += 2) s += partial2[b*CC + c];
  if (half) ired[c] = s;
  __syncthreads();
  if (!half){
    int sc = s + ired[c];
    double m = (double)sc / (double)NN;
    float pq = fminf(127.f, fmaxf(-128.f, (float)rint(m)));
    red[c] = pq * fcwf[c];
  }
  __syncthreads();
  for (int o=64;o>0;o>>=1){ if (t<o) red[t] += red[t+o]; __syncthreads(); }
  if (t==0){
    float v = rq16(red[0] + fcb16[0]);
    float o1 = v * 0.0625f;
    float sg = 1.f/(1.f + expf(-o1));
    float oq = fminf(127.f, fmaxf(-128.f, rintf(sg*16.f)));
    out[0] = oq * 0.0625f;
  }
}

extern "C" void kernel_launch(void* const* d_in, const int* in_sizes, int n_in,
                              void* d_out, int out_size, void* d_ws, size_t ws_size,
                              hipStream_t stream){
  (void)in_sizes; (void)n_in; (void)out_size;
  const float* x   = (const float*)d_in[0];
  const float* ea  = (const float*)d_in[1];
  const int*   ei  = (const int*)d_in[2];
  const float* W1  = (const float*)d_in[11];
  const float* W2  = (const float*)d_in[15];

  char* w = (char*)d_ws;
  auto alloc = [&](size_t bytes)->char*{
    char* p = w; w += (bytes + 255) & ~(size_t)255; return p;
  };
  short* h0        = (short*)alloc((size_t)NPAD*CC*2);
  short* h1        = (short*)alloc((size_t)NPAD*CC*2);
  signed char* hq8 = (signed char*)alloc((size_t)NPAD*CC);
  signed char* uq  = (signed char*)alloc((size_t)NPAD*CC);
  int2* adjq       = (int2*)alloc((size_t)PE*8);
  int* deg         = (int*)alloc(NN*4);
  int* offI        = (int*)alloc(NN*4);
  int* cursor      = (int*)alloc(NN*4);
  int* btot        = (int*)alloc(64*4);
  int* boff        = (int*)alloc(64*4);
  int* partial     = (int*)alloc((size_t)NBLK*CC*4);
  int* partial2    = (int*)alloc((size_t)R2*CC*4);
  signed char* w1q8= (signed char*)alloc((size_t)LL*CC*HH);
  signed char* w2q8= (signed char*)alloc((size_t)LL*CC*HH);
  float* nodeWf    = (float*)alloc(3*CC*4);
  float* nb16f     = (float*)alloc(CC*4);
  float* nbnwf     = (float*)alloc(CC*4);
  float* nbnb16f   = (float*)alloc(CC*4);
  float* b1q16f    = (float*)alloc(LL*HH*4);
  float* bnwf      = (float*)alloc(LL*HH*4);
  float* bnb16f    = (float*)alloc(LL*HH*4);
  float* b2q16f    = (float*)alloc(LL*CC*4);
  float* fcwf      = (float*)alloc(CC*4);
  float* fcb16f    = (float*)alloc(256);
  int4* epk        = (int4*)alloc(CC*16);
  size_t base_used = (size_t)(w - (char*)d_ws);
  // chunk-transposed edge features: 128B per padded slot (worst case ~176MB)
  bool TEQ = (ws_size >= base_used + (size_t)PE*CC + (16u<<20));
  signed char* eqt = TEQ ? (signed char*)alloc((size_t)PE*CC) : nullptr;

  hipMemsetAsync(deg, 0, NN*4, stream);
  hipMemsetAsync(adjq, 0, (size_t)PE*8, stream);   // zero pads (safe dup reads)

  k_qbig<<<(LL*CC*HH + 255)/256, 256, 0, stream>>>(W1, W2, w1q8, w2q8);

  QSArgs qa;
  auto setq = [&](int r, int idx, float* d, int n, float m){
    qa.q[r].s = (const float*)d_in[idx]; qa.q[r].d = d; qa.q[r].n = n; qa.q[r].m = m;
  };
  setq(0, 3,  nodeWf,  3*CC, 1.f);
  setq(1, 4,  nb16f,   CC,   16.f);
  setq(2, 7,  nbnwf,   CC,   1.f);
  setq(3, 8,  nbnb16f, CC,   16.f);
  setq(4, 12, b1q16f,  LL*HH, 16.f);
  setq(5, 13, bnwf,    LL*HH, 1.f);
  setq(6, 14, bnb16f,  LL*HH, 16.f);
  setq(7, 16, b2q16f,  LL*CC, 16.f);
  setq(8, 17, fcwf,    CC,   1.f);
  setq(9, 18, fcb16f,  1,    16.f);
  k_qsmall<<<4, 256, 0, stream>>>(qa);
  k_epki<<<1, 128, 0, stream>>>((const float*)d_in[5], (const float*)d_in[6],
                                (const float*)d_in[9], (const float*)d_in[10], epk);

  k_node_enc<<<(NN*CC)/256, 256, 0, stream>>>(x, nodeWf, nb16f, nbnwf, nbnb16f, h0, hq8);
  k_deg<<<(EE+255)/256, 256, 0, stream>>>(ei, deg);
  int nblk = (NN + 1023)/1024;
  k_scanA<<<nblk, 256, 0, stream>>>(deg, offI, btot);
  k_scanB<<<1, 64, 0, stream>>>(btot, boff, nblk);
  k_scanC<<<(NN+255)/256, 256, 0, stream>>>(boff, deg, offI, cursor);
  k_fill<<<(EE+255)/256, 256, 0, stream>>>(ei, ea, cursor, adjq);

  for (int l=0;l<LL;++l){
    const short* hi = (l & 1) ? h1 : h0;
    short* ho       = (l & 1) ? h0 : h1;
    if (!TEQ)
      k_msg<2><<<NN/4, 256, 0, stream>>>(offI, deg, adjq, epk, eqt, hq8, uq);
    else if (l == 0)
      k_msg<0><<<NN/4, 256, 0, stream>>>(offI, deg, adjq, epk, eqt, hq8, uq);
    else
      k_msg<1><<<NN/4, 256, 0, stream>>>(offI, deg, adjq, epk, eqt, hq8, uq);
    k_om<<<NBLK, 256, 0, stream>>>(l, uq, w1q8, b1q16f, bnwf, bnb16f,
                                   w2q8, b2q16f, hi, ho, hq8,
                                   (l == LL-1) ? partial : nullptr);
  }
  k_red<<<R2/2, 256, 0, stream>>>(partial, partial2);
  k_final<<<1, 256, 0, stream>>>(partial2, fcwf, fcb16f, (float*)d_out);
}